// Round 12
// baseline (99.249 us; speedup 1.0000x reference)
//
#include <hip/hip_runtime.h>

#define NB 1024

typedef _Float16 f16x8 __attribute__((ext_vector_type(8)));
typedef float f32x4 __attribute__((ext_vector_type(4)));

union ABu { uint4 u; f16x8 v; _Float16 h[8]; unsigned int w[4]; };

__device__ __forceinline__ unsigned int pkrtz(float a, float b) {
    __fp16 r2 __attribute__((ext_vector_type(2))) = __builtin_amdgcn_cvt_pkrtz(a, b);
    return __builtin_bit_cast(unsigned int, r2);
}

// ---- prep 1: A[p][n] = x[p] @ W0[:64,:],  C[q][n] = y[q] @ W0[64:,:] + b0 -> f16 ----
__global__ void prep_ac(const float* __restrict__ x, const float* __restrict__ y,
                        const float* __restrict__ W0, const float* __restrict__ b0,
                        _Float16* __restrict__ Af, _Float16* __restrict__ Cf) {
    __shared__ float row[64];
    int b = blockIdx.x;
    int t = threadIdx.x;
    bool isC = b >= 1024;
    int r = isC ? b - 1024 : b;
    const float* src = isC ? y : x;
    if (t < 64) row[t] = src[r * 64 + t];
    __syncthreads();
    const float* w = W0 + (isC ? 64 * 128 : 0);
    float acc = isC ? b0[t] : 0.f;
#pragma unroll
    for (int k = 0; k < 64; k++) acc += row[k] * w[k * 128 + t];
    (isC ? Cf : Af)[r * 128 + t] = (_Float16)acc;
}

// ---- prep 2: fragment-major f16 weight image (32768 elems = 64KB) ----
// chunk idx = ((ft*NKS + ks)*64 + lane)*8 + j ; W1 natural k; W2/3/4 sigma-permuted
__global__ void prep_img(const float* __restrict__ W1, const float* __restrict__ W2,
                         const float* __restrict__ W3, const float* __restrict__ W4,
                         _Float16* __restrict__ img) {
    int i = blockIdx.x * 256 + threadIdx.x;    // 0..32767
    float val;
    if (i < 16384) {           // W1: ft 0..7, ks 0..3
        int j = i & 7, cc = (i >> 3) & 15, gg = (i >> 7) & 3, ks = (i >> 9) & 3, ft = i >> 11;
        int k = 32 * ks + 8 * gg + j, n = 16 * ft + cc;
        val = W1[k * 128 + n];
    } else if (i < 24576) {    // W2: ft 0..3, ks 0..3 (K=128, sigma with H)
        int d = i - 16384;
        int j = d & 7, cc = (d >> 3) & 15, gg = (d >> 7) & 3, ks = (d >> 9) & 3, ft = d >> 11;
        int s = 32 * ks + 8 * gg + j;
        int H = s >> 6, sp = s & 63;
        int a = ((sp >> 5) & 1) | (((sp >> 2) & 1) << 1);
        int gs = (sp >> 3) & 3, rr = sp & 3;
        int fin = 64 * H + 16 * a + 4 * gs + rr, n = 16 * ft + cc;
        val = W2[fin * 64 + n];
    } else {                   // W3 / W4: ft 0..3, ks 0..1 (K=64, sigma)
        int d = (i < 28672) ? i - 24576 : i - 28672;
        const float* W = (i < 28672) ? W3 : W4;
        int j = d & 7, cc = (d >> 3) & 15, gg = (d >> 7) & 3, ks = (d >> 9) & 1, ft = d >> 10;
        int s = 32 * ks + 8 * gg + j;
        int a = ((s >> 5) & 1) | (((s >> 2) & 1) << 1);
        int gs = (s >> 3) & 3, rr = s & 3;
        int fin = 16 * a + 4 * gs + rr, n = 16 * ft + cc;
        val = W[fin * 64 + n];
    }
    img[i] = (_Float16)val;
}

#define MFMA(a, b, d) (d) = __builtin_amdgcn_mfma_f32_16x16x32_f16((a), (b), (d), 0, 0, 0)

// byte offsets into the LDS weight image
#define W2OFF 32768
#define W3OFF 49152
#define W4OFF 57344

// 64 pairs/wave (4p x 16q): image read amortized over 2x pairs vs R9.
__launch_bounds__(512, 2)
__global__ void critic_main(const _Float16* __restrict__ Af, const _Float16* __restrict__ Cf,
                            const _Float16* __restrict__ Wimg,
                            const float* __restrict__ b1, const float* __restrict__ b2,
                            const float* __restrict__ b3, const float* __restrict__ b4,
                            const float* __restrict__ W5, const float* __restrict__ b5,
                            float* __restrict__ out) {
    __shared__ _Float16 Wl[32768];   // 64KB staged weights, shared by 8 waves
    int tid = threadIdx.x;

    // stage weights: linear 64KB copy, coalesced, conflict-free
    {
        const uint4* src = (const uint4*)Wimg;
        uint4* dst = (uint4*)Wl;
#pragma unroll
        for (int r = 0; r < 8; r++) dst[r * 512 + tid] = src[r * 512 + tid];
    }
    __syncthreads();

    int w = tid >> 6, lane = tid & 63;
    int g = lane >> 4, c = lane & 15;
    int pw = (blockIdx.x >> 6) * 32 + w * 4;   // wave's 4 p rows
    int qb = (blockIdx.x & 63) * 16;           // block's 16 q cols
    const char* WB = (const char*)Wl;
    int lo = lane * 16;                         // the ONE dynamic LDS offset

    // ---- h0 B-frags: relu(A[p] + C[q]) packed f16.  4 pt -> 16 frags (64 VGPR) ----
    ABu af[4][4];   // [ks][pt]
#pragma unroll
    for (int ks = 0; ks < 4; ks++) {
        ABu cv; cv.u = *(const uint4*)&Cf[(qb + c) * 128 + ks * 32 + 8 * g];
#pragma unroll
        for (int pt = 0; pt < 4; pt++) {
            ABu av; av.u = *(const uint4*)&Af[(pw + pt) * 128 + ks * 32 + 8 * g];
            f16x8 s = av.v + cv.v;              // v_pk_add_f16
            f16x8 z = {};
            af[ks][pt].v = __builtin_elementwise_max(s, z);   // v_pk_max_f16
        }
    }

    // ---- W1 (128->128): eight 16-feat tiles; pkrtz epilogue into sigma-slot u32s ----
    ABu bh1[4][4];   // [ks'][pt]
#pragma unroll
    for (int ft = 0; ft < 8; ft++) {
        const int Hq = ft >> 2, a3 = ft & 3, ksp = a3 & 1, hi = a3 >> 1;
        f32x4 binit = *(const f32x4*)&b1[ft * 16 + 4 * g];
        f32x4 acc[4] = {binit, binit, binit, binit};
#pragma unroll
        for (int ks = 0; ks < 4; ks++) {
            ABu wf; wf.u = *(const uint4*)(WB + ft * 4096 + ks * 1024 + lo);
#pragma unroll
            for (int pt = 0; pt < 4; pt++) MFMA(wf.v, af[ks][pt].v, acc[pt]);
        }
#pragma unroll
        for (int pt = 0; pt < 4; pt++) {
            bh1[Hq * 2 + ksp][pt].w[hi * 2 + 0] =
                pkrtz(fmaxf(acc[pt][0], 0.f), fmaxf(acc[pt][1], 0.f));
            bh1[Hq * 2 + ksp][pt].w[hi * 2 + 1] =
                pkrtz(fmaxf(acc[pt][2], 0.f), fmaxf(acc[pt][3], 0.f));
        }
    }

    // ---- W2 (128->64): four 16-feat tiles ----
    ABu bh2[2][4];
#pragma unroll
    for (int ft = 0; ft < 4; ft++) {
        const int ksp = ft & 1, hi = ft >> 1;
        f32x4 binit = *(const f32x4*)&b2[ft * 16 + 4 * g];
        f32x4 acc[4] = {binit, binit, binit, binit};
#pragma unroll
        for (int ks = 0; ks < 4; ks++) {
            ABu wf; wf.u = *(const uint4*)(WB + W2OFF + ft * 4096 + ks * 1024 + lo);
#pragma unroll
            for (int pt = 0; pt < 4; pt++) MFMA(wf.v, bh1[ks][pt].v, acc[pt]);
        }
#pragma unroll
        for (int pt = 0; pt < 4; pt++) {
            bh2[ksp][pt].w[hi * 2 + 0] =
                pkrtz(fmaxf(acc[pt][0], 0.f), fmaxf(acc[pt][1], 0.f));
            bh2[ksp][pt].w[hi * 2 + 1] =
                pkrtz(fmaxf(acc[pt][2], 0.f), fmaxf(acc[pt][3], 0.f));
        }
    }

    // ---- W3 (64->64): four 16-feat tiles ----
    ABu bh3[2][4];
#pragma unroll
    for (int ft = 0; ft < 4; ft++) {
        const int ksp = ft & 1, hi = ft >> 1;
        f32x4 binit = *(const f32x4*)&b3[ft * 16 + 4 * g];
        f32x4 acc[4] = {binit, binit, binit, binit};
#pragma unroll
        for (int ks = 0; ks < 2; ks++) {
            ABu wf; wf.u = *(const uint4*)(WB + W3OFF + ft * 2048 + ks * 1024 + lo);
#pragma unroll
            for (int pt = 0; pt < 4; pt++) MFMA(wf.v, bh2[ks][pt].v, acc[pt]);
        }
#pragma unroll
        for (int pt = 0; pt < 4; pt++) {
            bh3[ksp][pt].w[hi * 2 + 0] =
                pkrtz(fmaxf(acc[pt][0], 0.f), fmaxf(acc[pt][1], 0.f));
            bh3[ksp][pt].w[hi * 2 + 1] =
                pkrtz(fmaxf(acc[pt][2], 0.f), fmaxf(acc[pt][3], 0.f));
        }
    }

    // ---- W4 (64->64) with W5 dot folded per tile ----
    float s0 = 0.f, s1 = 0.f, s2 = 0.f, s3 = 0.f;
#pragma unroll
    for (int ft = 0; ft < 4; ft++) {
        f32x4 binit = *(const f32x4*)&b4[ft * 16 + 4 * g];
        f32x4 ww    = *(const f32x4*)&W5[ft * 16 + 4 * g];
        f32x4 acc[4] = {binit, binit, binit, binit};
#pragma unroll
        for (int ks = 0; ks < 2; ks++) {
            ABu wf; wf.u = *(const uint4*)(WB + W4OFF + ft * 2048 + ks * 1024 + lo);
#pragma unroll
            for (int pt = 0; pt < 4; pt++) MFMA(wf.v, bh3[ks][pt].v, acc[pt]);
        }
#pragma unroll
        for (int r = 0; r < 4; r++) {
            s0 += fmaxf(acc[0][r], 0.f) * ww[r];
            s1 += fmaxf(acc[1][r], 0.f) * ww[r];
            s2 += fmaxf(acc[2][r], 0.f) * ww[r];
            s3 += fmaxf(acc[3][r], 0.f) * ww[r];
        }
    }

    // ---- reduce over g-lanes, write 4 outputs ----
    float b5s = b5[0];
    s0 += __shfl_xor(s0, 16); s0 += __shfl_xor(s0, 32);
    s1 += __shfl_xor(s1, 16); s1 += __shfl_xor(s1, 32);
    s2 += __shfl_xor(s2, 16); s2 += __shfl_xor(s2, 32);
    s3 += __shfl_xor(s3, 16); s3 += __shfl_xor(s3, 32);
    if (lane < 16) {
        out[(pw + 0) * NB + qb + c] = s0 + b5s;
        out[(pw + 1) * NB + qb + c] = s1 + b5s;
        out[(pw + 2) * NB + qb + c] = s2 + b5s;
        out[(pw + 3) * NB + qb + c] = s3 + b5s;
    }
}

extern "C" void kernel_launch(void* const* d_in, const int* in_sizes, int n_in,
                              void* d_out, int out_size, void* d_ws, size_t ws_size,
                              hipStream_t stream) {
    const float* x  = (const float*)d_in[0];
    const float* y  = (const float*)d_in[1];
    const float* W0 = (const float*)d_in[2];
    const float* b0 = (const float*)d_in[3];
    const float* W1 = (const float*)d_in[4];
    const float* b1 = (const float*)d_in[5];
    const float* W2 = (const float*)d_in[6];
    const float* b2 = (const float*)d_in[7];
    const float* W3 = (const float*)d_in[8];
    const float* b3 = (const float*)d_in[9];
    const float* W4 = (const float*)d_in[10];
    const float* b4 = (const float*)d_in[11];
    const float* W5 = (const float*)d_in[12];
    const float* b5 = (const float*)d_in[13];
    float* out = (float*)d_out;

    char* ws = (char*)d_ws;
    _Float16* Af   = (_Float16*)ws;                 // 1024*128 f16 = 256KB
    _Float16* Cf   = (_Float16*)(ws + 262144);      // 256KB
    _Float16* Wimg = (_Float16*)(ws + 524288);      // 64KB fragment-major image

    prep_ac<<<2048, 128, 0, stream>>>(x, y, W0, b0, Af, Cf);
    prep_img<<<128, 256, 0, stream>>>(W1, W2, W3, W4, Wimg);
    critic_main<<<2048, 512, 0, stream>>>(Af, Cf, Wimg,
                                          b1, b2, b3, b4, W5, b5, out);
}

// Round 13
// 80.021 us; speedup vs baseline: 1.2403x; 1.2403x over previous
//
#include <hip/hip_runtime.h>

#define NB 1024

typedef _Float16 f16x8 __attribute__((ext_vector_type(8)));
typedef float f32x4 __attribute__((ext_vector_type(4)));

union ABu { uint4 u; f16x8 v; _Float16 h[8]; unsigned int w[4]; };

__device__ __forceinline__ unsigned int pkrtz(float a, float b) {
    __fp16 r2 __attribute__((ext_vector_type(2))) = __builtin_amdgcn_cvt_pkrtz(a, b);
    return __builtin_bit_cast(unsigned int, r2);
}

// ---- prep 1: A[p][n] = x[p] @ W0[:64,:],  C[q][n] = y[q] @ W0[64:,:] + b0 -> f16 ----
__global__ void prep_ac(const float* __restrict__ x, const float* __restrict__ y,
                        const float* __restrict__ W0, const float* __restrict__ b0,
                        _Float16* __restrict__ Af, _Float16* __restrict__ Cf) {
    __shared__ float row[64];
    int b = blockIdx.x;
    int t = threadIdx.x;
    bool isC = b >= 1024;
    int r = isC ? b - 1024 : b;
    const float* src = isC ? y : x;
    if (t < 64) row[t] = src[r * 64 + t];
    __syncthreads();
    const float* w = W0 + (isC ? 64 * 128 : 0);
    float acc = isC ? b0[t] : 0.f;
#pragma unroll
    for (int k = 0; k < 64; k++) acc += row[k] * w[k * 128 + t];
    (isC ? Cf : Af)[r * 128 + t] = (_Float16)acc;
}

// ---- prep 2: fragment-major f16 weight image (32768 elems = 64KB) ----
// chunk idx = ((ft*NKS + ks)*64 + lane)*8 + j ; W1 natural k; W2/3/4 sigma-permuted
__global__ void prep_img(const float* __restrict__ W1, const float* __restrict__ W2,
                         const float* __restrict__ W3, const float* __restrict__ W4,
                         _Float16* __restrict__ img) {
    int i = blockIdx.x * 256 + threadIdx.x;    // 0..32767
    float val;
    if (i < 16384) {           // W1: ft 0..7, ks 0..3
        int j = i & 7, cc = (i >> 3) & 15, gg = (i >> 7) & 3, ks = (i >> 9) & 3, ft = i >> 11;
        int k = 32 * ks + 8 * gg + j, n = 16 * ft + cc;
        val = W1[k * 128 + n];
    } else if (i < 24576) {    // W2: ft 0..3, ks 0..3 (K=128, sigma with H)
        int d = i - 16384;
        int j = d & 7, cc = (d >> 3) & 15, gg = (d >> 7) & 3, ks = (d >> 9) & 3, ft = d >> 11;
        int s = 32 * ks + 8 * gg + j;
        int H = s >> 6, sp = s & 63;
        int a = ((sp >> 5) & 1) | (((sp >> 2) & 1) << 1);
        int gs = (sp >> 3) & 3, rr = sp & 3;
        int fin = 64 * H + 16 * a + 4 * gs + rr, n = 16 * ft + cc;
        val = W2[fin * 64 + n];
    } else {                   // W3 / W4: ft 0..3, ks 0..1 (K=64, sigma)
        int d = (i < 28672) ? i - 24576 : i - 28672;
        const float* W = (i < 28672) ? W3 : W4;
        int j = d & 7, cc = (d >> 3) & 15, gg = (d >> 7) & 3, ks = (d >> 9) & 1, ft = d >> 10;
        int s = 32 * ks + 8 * gg + j;
        int a = ((s >> 5) & 1) | (((s >> 2) & 1) << 1);
        int gs = (s >> 3) & 3, rr = s & 3;
        int fin = 16 * a + 4 * gs + rr, n = 16 * ft + cc;
        val = W[fin * 64 + n];
    }
    img[i] = (_Float16)val;
}

#define MFMA(a, b, d) (d) = __builtin_amdgcn_mfma_f32_16x16x32_f16((a), (b), (d), 0, 0, 0)

// byte offsets into the LDS weight image
#define W2OFF 32768
#define W3OFF 49152
#define W4OFF 57344

__launch_bounds__(512, 4)
__global__ void critic_main(const _Float16* __restrict__ Af, const _Float16* __restrict__ Cf,
                            const _Float16* __restrict__ Wimg,
                            const float* __restrict__ b1, const float* __restrict__ b2,
                            const float* __restrict__ b3, const float* __restrict__ b4,
                            const float* __restrict__ W5, const float* __restrict__ b5,
                            float* __restrict__ out) {
    __shared__ _Float16 Wl[32768];   // 64KB staged weights, shared by 8 waves
    int tid = threadIdx.x;

    // stage weights: linear 64KB copy, coalesced, conflict-free
    {
        const uint4* src = (const uint4*)Wimg;
        uint4* dst = (uint4*)Wl;
#pragma unroll
        for (int r = 0; r < 8; r++) dst[r * 512 + tid] = src[r * 512 + tid];
    }
    __syncthreads();

    int w = tid >> 6, lane = tid & 63;
    int g = lane >> 4, c = lane & 15;
    int pw = (blockIdx.x >> 6) * 16 + w * 2;   // wave's 2 p rows
    int qb = (blockIdx.x & 63) * 16;           // block's 16 q cols
    const char* WB = (const char*)Wl;
    int lo = lane * 16;                         // the ONE dynamic LDS offset

    // ---- h0 B-frags: relu(A[p] + C[q]) in packed f16 ----
    ABu af[4][2];   // [ks][pt]
#pragma unroll
    for (int ks = 0; ks < 4; ks++) {
        ABu cv; cv.u = *(const uint4*)&Cf[(qb + c) * 128 + ks * 32 + 8 * g];
#pragma unroll
        for (int pt = 0; pt < 2; pt++) {
            ABu av; av.u = *(const uint4*)&Af[(pw + pt) * 128 + ks * 32 + 8 * g];
            f16x8 s = av.v + cv.v;              // v_pk_add_f16
            f16x8 z = {};
            af[ks][pt].v = __builtin_elementwise_max(s, z);   // v_pk_max_f16
        }
    }

    // ---- W1 (128->128): eight 16-feat tiles; pkrtz epilogue into sigma-slot u32s ----
    ABu bh1[4][2];   // [ks'][pt]
#pragma unroll
    for (int ft = 0; ft < 8; ft++) {
        const int Hq = ft >> 2, a3 = ft & 3, ksp = a3 & 1, hi = a3 >> 1;
        f32x4 binit = *(const f32x4*)&b1[ft * 16 + 4 * g];
        f32x4 acc[2] = {binit, binit};
#pragma unroll
        for (int ks = 0; ks < 4; ks++) {
            ABu wf; wf.u = *(const uint4*)(WB + ft * 4096 + ks * 1024 + lo);
#pragma unroll
            for (int pt = 0; pt < 2; pt++) MFMA(wf.v, af[ks][pt].v, acc[pt]);
        }
#pragma unroll
        for (int pt = 0; pt < 2; pt++) {
            bh1[Hq * 2 + ksp][pt].w[hi * 2 + 0] =
                pkrtz(fmaxf(acc[pt][0], 0.f), fmaxf(acc[pt][1], 0.f));
            bh1[Hq * 2 + ksp][pt].w[hi * 2 + 1] =
                pkrtz(fmaxf(acc[pt][2], 0.f), fmaxf(acc[pt][3], 0.f));
        }
    }

    // ---- W2 (128->64): four 16-feat tiles ----
    ABu bh2[2][2];
#pragma unroll
    for (int ft = 0; ft < 4; ft++) {
        const int ksp = ft & 1, hi = ft >> 1;
        f32x4 binit = *(const f32x4*)&b2[ft * 16 + 4 * g];
        f32x4 acc[2] = {binit, binit};
#pragma unroll
        for (int ks = 0; ks < 4; ks++) {
            ABu wf; wf.u = *(const uint4*)(WB + W2OFF + ft * 4096 + ks * 1024 + lo);
#pragma unroll
            for (int pt = 0; pt < 2; pt++) MFMA(wf.v, bh1[ks][pt].v, acc[pt]);
        }
#pragma unroll
        for (int pt = 0; pt < 2; pt++) {
            bh2[ksp][pt].w[hi * 2 + 0] =
                pkrtz(fmaxf(acc[pt][0], 0.f), fmaxf(acc[pt][1], 0.f));
            bh2[ksp][pt].w[hi * 2 + 1] =
                pkrtz(fmaxf(acc[pt][2], 0.f), fmaxf(acc[pt][3], 0.f));
        }
    }

    // ---- W3 (64->64): four 16-feat tiles ----
    ABu bh3[2][2];
#pragma unroll
    for (int ft = 0; ft < 4; ft++) {
        const int ksp = ft & 1, hi = ft >> 1;
        f32x4 binit = *(const f32x4*)&b3[ft * 16 + 4 * g];
        f32x4 acc[2] = {binit, binit};
#pragma unroll
        for (int ks = 0; ks < 2; ks++) {
            ABu wf; wf.u = *(const uint4*)(WB + W3OFF + ft * 2048 + ks * 1024 + lo);
#pragma unroll
            for (int pt = 0; pt < 2; pt++) MFMA(wf.v, bh2[ks][pt].v, acc[pt]);
        }
#pragma unroll
        for (int pt = 0; pt < 2; pt++) {
            bh3[ksp][pt].w[hi * 2 + 0] =
                pkrtz(fmaxf(acc[pt][0], 0.f), fmaxf(acc[pt][1], 0.f));
            bh3[ksp][pt].w[hi * 2 + 1] =
                pkrtz(fmaxf(acc[pt][2], 0.f), fmaxf(acc[pt][3], 0.f));
        }
    }

    // ---- W4 (64->64) with W5 dot folded per tile ----
    float s0 = 0.f, s1 = 0.f;
#pragma unroll
    for (int ft = 0; ft < 4; ft++) {
        f32x4 binit = *(const f32x4*)&b4[ft * 16 + 4 * g];
        f32x4 ww    = *(const f32x4*)&W5[ft * 16 + 4 * g];
        f32x4 acc[2] = {binit, binit};
#pragma unroll
        for (int ks = 0; ks < 2; ks++) {
            ABu wf; wf.u = *(const uint4*)(WB + W4OFF + ft * 2048 + ks * 1024 + lo);
#pragma unroll
            for (int pt = 0; pt < 2; pt++) MFMA(wf.v, bh3[ks][pt].v, acc[pt]);
        }
#pragma unroll
        for (int r = 0; r < 4; r++) {
            s0 += fmaxf(acc[0][r], 0.f) * ww[r];
            s1 += fmaxf(acc[1][r], 0.f) * ww[r];
        }
    }

    // ---- reduce over g-lanes, write outputs ----
    float b5s = b5[0];
    s0 += __shfl_xor(s0, 16); s0 += __shfl_xor(s0, 32);
    s1 += __shfl_xor(s1, 16); s1 += __shfl_xor(s1, 32);
    if (lane < 16) {
        out[(pw + 0) * NB + qb + c] = s0 + b5s;
        out[(pw + 1) * NB + qb + c] = s1 + b5s;
    }
}

extern "C" void kernel_launch(void* const* d_in, const int* in_sizes, int n_in,
                              void* d_out, int out_size, void* d_ws, size_t ws_size,
                              hipStream_t stream) {
    const float* x  = (const float*)d_in[0];
    const float* y  = (const float*)d_in[1];
    const float* W0 = (const float*)d_in[2];
    const float* b0 = (const float*)d_in[3];
    const float* W1 = (const float*)d_in[4];
    const float* b1 = (const float*)d_in[5];
    const float* W2 = (const float*)d_in[6];
    const float* b2 = (const float*)d_in[7];
    const float* W3 = (const float*)d_in[8];
    const float* b3 = (const float*)d_in[9];
    const float* W4 = (const float*)d_in[10];
    const float* b4 = (const float*)d_in[11];
    const float* W5 = (const float*)d_in[12];
    const float* b5 = (const float*)d_in[13];
    float* out = (float*)d_out;

    char* ws = (char*)d_ws;
    _Float16* Af   = (_Float16*)ws;                 // 1024*128 f16 = 256KB
    _Float16* Cf   = (_Float16*)(ws + 262144);      // 256KB
    _Float16* Wimg = (_Float16*)(ws + 524288);      // 64KB fragment-major image

    prep_ac<<<2048, 128, 0, stream>>>(x, y, W0, b0, Af, Cf);
    prep_img<<<128, 256, 0, stream>>>(W1, W2, W3, W4, Wimg);
    critic_main<<<4096, 512, 0, stream>>>(Af, Cf, Wimg,
                                          b1, b2, b3, b4, W5, b5, out);
}

// Round 14
// 79.122 us; speedup vs baseline: 1.2544x; 1.0114x over previous
//
#include <hip/hip_runtime.h>

#define NB 1024

typedef _Float16 f16x8 __attribute__((ext_vector_type(8)));
typedef _Float16 f16x2v __attribute__((ext_vector_type(2)));
typedef float f32x4 __attribute__((ext_vector_type(4)));

union ABu { uint4 u; f16x8 v; _Float16 h[8]; unsigned int w[4]; };

__device__ __forceinline__ unsigned int pkrtz(float a, float b) {
    __fp16 r2 __attribute__((ext_vector_type(2))) = __builtin_amdgcn_cvt_pkrtz(a, b);
    return __builtin_bit_cast(unsigned int, r2);
}
__device__ __forceinline__ unsigned int pkmax0(unsigned int a) {
    f16x2v v = __builtin_bit_cast(f16x2v, a);
    f16x2v z = {};
    v = __builtin_elementwise_max(v, z);     // v_pk_max_f16
    return __builtin_bit_cast(unsigned int, v);
}

// ---- prep 1: A[p][n] = x[p] @ W0[:64,:],  C[q][n] = y[q] @ W0[64:,:] + b0 -> f16 ----
__global__ void prep_ac(const float* __restrict__ x, const float* __restrict__ y,
                        const float* __restrict__ W0, const float* __restrict__ b0,
                        _Float16* __restrict__ Af, _Float16* __restrict__ Cf) {
    __shared__ float row[64];
    int b = blockIdx.x;
    int t = threadIdx.x;
    bool isC = b >= 1024;
    int r = isC ? b - 1024 : b;
    const float* src = isC ? y : x;
    if (t < 64) row[t] = src[r * 64 + t];
    __syncthreads();
    const float* w = W0 + (isC ? 64 * 128 : 0);
    float acc = isC ? b0[t] : 0.f;
#pragma unroll
    for (int k = 0; k < 64; k++) acc += row[k] * w[k * 128 + t];
    (isC ? Cf : Af)[r * 128 + t] = (_Float16)acc;
}

// ---- prep 2: fragment-major f16 weight image (32768 elems = 64KB) ----
// chunk idx = ((ft*NKS + ks)*64 + lane)*8 + j ; W1 natural k; W2/3/4 sigma-permuted
__global__ void prep_img(const float* __restrict__ W1, const float* __restrict__ W2,
                         const float* __restrict__ W3, const float* __restrict__ W4,
                         _Float16* __restrict__ img) {
    int i = blockIdx.x * 256 + threadIdx.x;    // 0..32767
    float val;
    if (i < 16384) {           // W1: ft 0..7, ks 0..3
        int j = i & 7, cc = (i >> 3) & 15, gg = (i >> 7) & 3, ks = (i >> 9) & 3, ft = i >> 11;
        int k = 32 * ks + 8 * gg + j, n = 16 * ft + cc;
        val = W1[k * 128 + n];
    } else if (i < 24576) {    // W2: ft 0..3, ks 0..3 (K=128, sigma with H)
        int d = i - 16384;
        int j = d & 7, cc = (d >> 3) & 15, gg = (d >> 7) & 3, ks = (d >> 9) & 3, ft = d >> 11;
        int s = 32 * ks + 8 * gg + j;
        int H = s >> 6, sp = s & 63;
        int a = ((sp >> 5) & 1) | (((sp >> 2) & 1) << 1);
        int gs = (sp >> 3) & 3, rr = sp & 3;
        int fin = 64 * H + 16 * a + 4 * gs + rr, n = 16 * ft + cc;
        val = W2[fin * 64 + n];
    } else {                   // W3 / W4: ft 0..3, ks 0..1 (K=64, sigma)
        int d = (i < 28672) ? i - 24576 : i - 28672;
        const float* W = (i < 28672) ? W3 : W4;
        int j = d & 7, cc = (d >> 3) & 15, gg = (d >> 7) & 3, ks = (d >> 9) & 1, ft = d >> 10;
        int s = 32 * ks + 8 * gg + j;
        int a = ((s >> 5) & 1) | (((s >> 2) & 1) << 1);
        int gs = (s >> 3) & 3, rr = s & 3;
        int fin = 16 * a + 4 * gs + rr, n = 16 * ft + cc;
        val = W[fin * 64 + n];
    }
    img[i] = (_Float16)val;
}

#define MFMA(a, b, d) (d) = __builtin_amdgcn_mfma_f32_16x16x32_f16((a), (b), (d), 0, 0, 0)

// byte offsets into the LDS weight image
#define W2OFF 32768
#define W3OFF 49152
#define W4OFF 57344

__launch_bounds__(512, 4)
__global__ void critic_main(const _Float16* __restrict__ Af, const _Float16* __restrict__ Cf,
                            const _Float16* __restrict__ Wimg,
                            const float* __restrict__ b1, const float* __restrict__ b2,
                            const float* __restrict__ b3, const float* __restrict__ b4,
                            const float* __restrict__ W5, const float* __restrict__ b5,
                            float* __restrict__ out) {
    __shared__ _Float16 Wl[32768];   // 64KB staged weights, shared by 8 waves
    int tid = threadIdx.x;
    int w = tid >> 6, lane = tid & 63;
    int g = lane >> 4, c = lane & 15;
    int pw = (blockIdx.x >> 6) * 16 + w * 2;   // wave's 2 p rows
    int qb = (blockIdx.x & 63) * 16;           // block's 16 q cols

    // issue staging loads first (latency overlapped with af build below)
    uint4 st[8];
    {
        const uint4* src = (const uint4*)Wimg;
#pragma unroll
        for (int r = 0; r < 8; r++) st[r] = src[r * 512 + tid];
    }

    // ---- h0 B-frags: relu(A[p] + C[q]) packed f16 — pure-global, runs under staging latency ----
    ABu af[4][2];   // [ks][pt]
#pragma unroll
    for (int ks = 0; ks < 4; ks++) {
        ABu cv; cv.u = *(const uint4*)&Cf[(qb + c) * 128 + ks * 32 + 8 * g];
#pragma unroll
        for (int pt = 0; pt < 2; pt++) {
            ABu av; av.u = *(const uint4*)&Af[(pw + pt) * 128 + ks * 32 + 8 * g];
            f16x8 s = av.v + cv.v;              // v_pk_add_f16
            f16x8 z = {};
            af[ks][pt].v = __builtin_elementwise_max(s, z);   // v_pk_max_f16
        }
    }

    // complete staging, then barrier
    {
        uint4* dst = (uint4*)Wl;
#pragma unroll
        for (int r = 0; r < 8; r++) dst[r * 512 + tid] = st[r];
    }
    __syncthreads();

    const char* WB = (const char*)Wl;
    int lo = lane * 16;                         // the ONE dynamic LDS offset

    // ---- W1 (128->128): eight 16-feat tiles; batched reads + pure-MFMA cluster ----
    ABu bh1[4][2];   // [ks'][pt]
#pragma unroll
    for (int ft = 0; ft < 8; ft++) {
        const int Hq = ft >> 2, a3 = ft & 3, ksp = a3 & 1, hi = a3 >> 1;
        f32x4 binit = *(const f32x4*)&b1[ft * 16 + 4 * g];
        f32x4 acc[2] = {binit, binit};
        ABu wf[4];
#pragma unroll
        for (int ks = 0; ks < 4; ks++)
            wf[ks].u = *(const uint4*)(WB + ft * 4096 + ks * 1024 + lo);
        __builtin_amdgcn_s_setprio(1);
#pragma unroll
        for (int ks = 0; ks < 4; ks++)
#pragma unroll
            for (int pt = 0; pt < 2; pt++) MFMA(wf[ks].v, af[ks][pt].v, acc[pt]);
        __builtin_amdgcn_s_setprio(0);
#pragma unroll
        for (int pt = 0; pt < 2; pt++) {
            bh1[Hq * 2 + ksp][pt].w[hi * 2 + 0] = pkmax0(pkrtz(acc[pt][0], acc[pt][1]));
            bh1[Hq * 2 + ksp][pt].w[hi * 2 + 1] = pkmax0(pkrtz(acc[pt][2], acc[pt][3]));
        }
    }

    // ---- W2 (128->64): four 16-feat tiles ----
    ABu bh2[2][2];
#pragma unroll
    for (int ft = 0; ft < 4; ft++) {
        const int ksp = ft & 1, hi = ft >> 1;
        f32x4 binit = *(const f32x4*)&b2[ft * 16 + 4 * g];
        f32x4 acc[2] = {binit, binit};
        ABu wf[4];
#pragma unroll
        for (int ks = 0; ks < 4; ks++)
            wf[ks].u = *(const uint4*)(WB + W2OFF + ft * 4096 + ks * 1024 + lo);
        __builtin_amdgcn_s_setprio(1);
#pragma unroll
        for (int ks = 0; ks < 4; ks++)
#pragma unroll
            for (int pt = 0; pt < 2; pt++) MFMA(wf[ks].v, bh1[ks][pt].v, acc[pt]);
        __builtin_amdgcn_s_setprio(0);
#pragma unroll
        for (int pt = 0; pt < 2; pt++) {
            bh2[ksp][pt].w[hi * 2 + 0] = pkmax0(pkrtz(acc[pt][0], acc[pt][1]));
            bh2[ksp][pt].w[hi * 2 + 1] = pkmax0(pkrtz(acc[pt][2], acc[pt][3]));
        }
    }

    // ---- W3 (64->64): four 16-feat tiles ----
    ABu bh3[2][2];
#pragma unroll
    for (int ft = 0; ft < 4; ft++) {
        const int ksp = ft & 1, hi = ft >> 1;
        f32x4 binit = *(const f32x4*)&b3[ft * 16 + 4 * g];
        f32x4 acc[2] = {binit, binit};
        ABu wf[2];
#pragma unroll
        for (int ks = 0; ks < 2; ks++)
            wf[ks].u = *(const uint4*)(WB + W3OFF + ft * 2048 + ks * 1024 + lo);
        __builtin_amdgcn_s_setprio(1);
#pragma unroll
        for (int ks = 0; ks < 2; ks++)
#pragma unroll
            for (int pt = 0; pt < 2; pt++) MFMA(wf[ks].v, bh2[ks][pt].v, acc[pt]);
        __builtin_amdgcn_s_setprio(0);
#pragma unroll
        for (int pt = 0; pt < 2; pt++) {
            bh3[ksp][pt].w[hi * 2 + 0] = pkmax0(pkrtz(acc[pt][0], acc[pt][1]));
            bh3[ksp][pt].w[hi * 2 + 1] = pkmax0(pkrtz(acc[pt][2], acc[pt][3]));
        }
    }

    // ---- W4 (64->64) with W5 dot folded per tile (f32 epilogue) ----
    float s0 = 0.f, s1 = 0.f;
#pragma unroll
    for (int ft = 0; ft < 4; ft++) {
        f32x4 binit = *(const f32x4*)&b4[ft * 16 + 4 * g];
        f32x4 ww    = *(const f32x4*)&W5[ft * 16 + 4 * g];
        f32x4 acc[2] = {binit, binit};
        ABu wf[2];
#pragma unroll
        for (int ks = 0; ks < 2; ks++)
            wf[ks].u = *(const uint4*)(WB + W4OFF + ft * 2048 + ks * 1024 + lo);
        __builtin_amdgcn_s_setprio(1);
#pragma unroll
        for (int ks = 0; ks < 2; ks++)
#pragma unroll
            for (int pt = 0; pt < 2; pt++) MFMA(wf[ks].v, bh3[ks][pt].v, acc[pt]);
        __builtin_amdgcn_s_setprio(0);
#pragma unroll
        for (int r = 0; r < 4; r++) {
            s0 += fmaxf(acc[0][r], 0.f) * ww[r];
            s1 += fmaxf(acc[1][r], 0.f) * ww[r];
        }
    }

    // ---- reduce over g-lanes, write outputs ----
    float b5s = b5[0];
    s0 += __shfl_xor(s0, 16); s0 += __shfl_xor(s0, 32);
    s1 += __shfl_xor(s1, 16); s1 += __shfl_xor(s1, 32);
    if (lane < 16) {
        out[(pw + 0) * NB + qb + c] = s0 + b5s;
        out[(pw + 1) * NB + qb + c] = s1 + b5s;
    }
}

extern "C" void kernel_launch(void* const* d_in, const int* in_sizes, int n_in,
                              void* d_out, int out_size, void* d_ws, size_t ws_size,
                              hipStream_t stream) {
    const float* x  = (const float*)d_in[0];
    const float* y  = (const float*)d_in[1];
    const float* W0 = (const float*)d_in[2];
    const float* b0 = (const float*)d_in[3];
    const float* W1 = (const float*)d_in[4];
    const float* b1 = (const float*)d_in[5];
    const float* W2 = (const float*)d_in[6];
    const float* b2 = (const float*)d_in[7];
    const float* W3 = (const float*)d_in[8];
    const float* b3 = (const float*)d_in[9];
    const float* W4 = (const float*)d_in[10];
    const float* b4 = (const float*)d_in[11];
    const float* W5 = (const float*)d_in[12];
    const float* b5 = (const float*)d_in[13];
    float* out = (float*)d_out;

    char* ws = (char*)d_ws;
    _Float16* Af   = (_Float16*)ws;                 // 1024*128 f16 = 256KB
    _Float16* Cf   = (_Float16*)(ws + 262144);      // 256KB
    _Float16* Wimg = (_Float16*)(ws + 524288);      // 64KB fragment-major image

    prep_ac<<<2048, 128, 0, stream>>>(x, y, W0, b0, Af, Cf);
    prep_img<<<128, 256, 0, stream>>>(W1, W2, W3, W4, Wimg);
    critic_main<<<4096, 512, 0, stream>>>(Af, Cf, Wimg,
                                          b1, b2, b3, b4, W5, b5, out);
}

// Round 15
// 78.319 us; speedup vs baseline: 1.2672x; 1.0103x over previous
//
#include <hip/hip_runtime.h>

#define NB 1024

typedef _Float16 f16x8 __attribute__((ext_vector_type(8)));
typedef _Float16 f16x2v __attribute__((ext_vector_type(2)));
typedef float f32x4 __attribute__((ext_vector_type(4)));

union ABu { uint4 u; f16x8 v; _Float16 h[8]; unsigned int w[4]; };

__device__ __forceinline__ unsigned int pkrtz(float a, float b) {
    __fp16 r2 __attribute__((ext_vector_type(2))) = __builtin_amdgcn_cvt_pkrtz(a, b);
    return __builtin_bit_cast(unsigned int, r2);
}
__device__ __forceinline__ unsigned int pkmax0(unsigned int a) {
    f16x2v v = __builtin_bit_cast(f16x2v, a);
    f16x2v z = {};
    v = __builtin_elementwise_max(v, z);     // v_pk_max_f16
    return __builtin_bit_cast(unsigned int, v);
}

// ---- prep 1: A[p][n] = x[p] @ W0[:64,:],  C[q][n] = y[q] @ W0[64:,:] + b0 -> f16 ----
__global__ void prep_ac(const float* __restrict__ x, const float* __restrict__ y,
                        const float* __restrict__ W0, const float* __restrict__ b0,
                        _Float16* __restrict__ Af, _Float16* __restrict__ Cf) {
    __shared__ float row[64];
    int b = blockIdx.x;
    int t = threadIdx.x;
    bool isC = b >= 1024;
    int r = isC ? b - 1024 : b;
    const float* src = isC ? y : x;
    if (t < 64) row[t] = src[r * 64 + t];
    __syncthreads();
    const float* w = W0 + (isC ? 64 * 128 : 0);
    float acc = isC ? b0[t] : 0.f;
#pragma unroll
    for (int k = 0; k < 64; k++) acc += row[k] * w[k * 128 + t];
    (isC ? Cf : Af)[r * 128 + t] = (_Float16)acc;
}

// ---- prep 2: fragment-major f16 weight image (32768 elems = 64KB) ----
// chunk idx = ((ft*NKS + ks)*64 + lane)*8 + j ; W1 natural k; W2/3/4 sigma-permuted
__global__ void prep_img(const float* __restrict__ W1, const float* __restrict__ W2,
                         const float* __restrict__ W3, const float* __restrict__ W4,
                         _Float16* __restrict__ img) {
    int i = blockIdx.x * 256 + threadIdx.x;    // 0..32767
    float val;
    if (i < 16384) {           // W1: ft 0..7, ks 0..3
        int j = i & 7, cc = (i >> 3) & 15, gg = (i >> 7) & 3, ks = (i >> 9) & 3, ft = i >> 11;
        int k = 32 * ks + 8 * gg + j, n = 16 * ft + cc;
        val = W1[k * 128 + n];
    } else if (i < 24576) {    // W2: ft 0..3, ks 0..3 (K=128, sigma with H)
        int d = i - 16384;
        int j = d & 7, cc = (d >> 3) & 15, gg = (d >> 7) & 3, ks = (d >> 9) & 3, ft = d >> 11;
        int s = 32 * ks + 8 * gg + j;
        int H = s >> 6, sp = s & 63;
        int a = ((sp >> 5) & 1) | (((sp >> 2) & 1) << 1);
        int gs = (sp >> 3) & 3, rr = sp & 3;
        int fin = 64 * H + 16 * a + 4 * gs + rr, n = 16 * ft + cc;
        val = W2[fin * 64 + n];
    } else {                   // W3 / W4: ft 0..3, ks 0..1 (K=64, sigma)
        int d = (i < 28672) ? i - 24576 : i - 28672;
        const float* W = (i < 28672) ? W3 : W4;
        int j = d & 7, cc = (d >> 3) & 15, gg = (d >> 7) & 3, ks = (d >> 9) & 1, ft = d >> 10;
        int s = 32 * ks + 8 * gg + j;
        int a = ((s >> 5) & 1) | (((s >> 2) & 1) << 1);
        int gs = (s >> 3) & 3, rr = s & 3;
        int fin = 16 * a + 4 * gs + rr, n = 16 * ft + cc;
        val = W[fin * 64 + n];
    }
    img[i] = (_Float16)val;
}

#define MFMA(a, b, d) (d) = __builtin_amdgcn_mfma_f32_16x16x32_f16((a), (b), (d), 0, 0, 0)

// byte offsets into the LDS weight image
#define W2OFF 32768
#define W3OFF 49152
#define W4OFF 57344

__launch_bounds__(512, 4)
__global__ void critic_main(const _Float16* __restrict__ Af, const _Float16* __restrict__ Cf,
                            const _Float16* __restrict__ Wimg,
                            const float* __restrict__ b1, const float* __restrict__ b2,
                            const float* __restrict__ b3, const float* __restrict__ b4,
                            const float* __restrict__ W5, const float* __restrict__ b5,
                            float* __restrict__ out) {
    __shared__ _Float16 Wl[32768];   // 64KB staged weights, shared by 8 waves
    int tid = threadIdx.x;
    int w = tid >> 6, lane = tid & 63;
    int g = lane >> 4, c = lane & 15;
    int pw = (blockIdx.x >> 6) * 16 + w * 2;   // wave's 2 p rows
    int qb = (blockIdx.x & 63) * 16;           // block's 16 q cols

    // issue staging loads first (latency overlapped with af build below)
    uint4 st[8];
    {
        const uint4* src = (const uint4*)Wimg;
#pragma unroll
        for (int r = 0; r < 8; r++) st[r] = src[r * 512 + tid];
    }

    // ---- h0 B-frags: relu(A[p] + C[q]) packed f16 — pure-global, runs under staging latency ----
    ABu af[4][2];   // [ks][pt]
#pragma unroll
    for (int ks = 0; ks < 4; ks++) {
        ABu cv; cv.u = *(const uint4*)&Cf[(qb + c) * 128 + ks * 32 + 8 * g];
#pragma unroll
        for (int pt = 0; pt < 2; pt++) {
            ABu av; av.u = *(const uint4*)&Af[(pw + pt) * 128 + ks * 32 + 8 * g];
            f16x8 s = av.v + cv.v;              // v_pk_add_f16
            f16x8 z = {};
            af[ks][pt].v = __builtin_elementwise_max(s, z);   // v_pk_max_f16
        }
    }

    // complete staging, then barrier
    {
        uint4* dst = (uint4*)Wl;
#pragma unroll
        for (int r = 0; r < 8; r++) dst[r * 512 + tid] = st[r];
    }
    __syncthreads();

    const char* WB = (const char*)Wl;
    int lo = lane * 16;                         // the ONE dynamic LDS offset

    // ---- W1 (128->128): 4 tile-PAIRS; 8 batched reads -> 16-MFMA cluster (4 indep chains) ----
    ABu bh1[4][2];   // [ks'][pt]
#pragma unroll
    for (int fp = 0; fp < 4; fp++) {
        const int f0 = 2 * fp, f1 = 2 * fp + 1;
        f32x4 b0v = *(const f32x4*)&b1[f0 * 16 + 4 * g];
        f32x4 b1v = *(const f32x4*)&b1[f1 * 16 + 4 * g];
        f32x4 acc[2][2] = {{b0v, b0v}, {b1v, b1v}};   // [tile][pt]
        ABu wf[2][4];
#pragma unroll
        for (int ks = 0; ks < 4; ks++) {
            wf[0][ks].u = *(const uint4*)(WB + f0 * 4096 + ks * 1024 + lo);
            wf[1][ks].u = *(const uint4*)(WB + f1 * 4096 + ks * 1024 + lo);
        }
        __builtin_amdgcn_s_setprio(1);
#pragma unroll
        for (int ks = 0; ks < 4; ks++)
#pragma unroll
            for (int t = 0; t < 2; t++)
#pragma unroll
                for (int pt = 0; pt < 2; pt++) MFMA(wf[t][ks].v, af[ks][pt].v, acc[t][pt]);
        __builtin_amdgcn_s_setprio(0);
#pragma unroll
        for (int t = 0; t < 2; t++) {
            const int ft = 2 * fp + t;
            const int Hq = ft >> 2, a3 = ft & 3, ksp = a3 & 1, hi = a3 >> 1;
#pragma unroll
            for (int pt = 0; pt < 2; pt++) {
                bh1[Hq * 2 + ksp][pt].w[hi * 2 + 0] = pkmax0(pkrtz(acc[t][pt][0], acc[t][pt][1]));
                bh1[Hq * 2 + ksp][pt].w[hi * 2 + 1] = pkmax0(pkrtz(acc[t][pt][2], acc[t][pt][3]));
            }
        }
    }

    // ---- W2 (128->64): 2 tile-pairs ----
    ABu bh2[2][2];
#pragma unroll
    for (int fp = 0; fp < 2; fp++) {
        const int f0 = 2 * fp, f1 = 2 * fp + 1;
        f32x4 b0v = *(const f32x4*)&b2[f0 * 16 + 4 * g];
        f32x4 b1v = *(const f32x4*)&b2[f1 * 16 + 4 * g];
        f32x4 acc[2][2] = {{b0v, b0v}, {b1v, b1v}};
        ABu wf[2][4];
#pragma unroll
        for (int ks = 0; ks < 4; ks++) {
            wf[0][ks].u = *(const uint4*)(WB + W2OFF + f0 * 4096 + ks * 1024 + lo);
            wf[1][ks].u = *(const uint4*)(WB + W2OFF + f1 * 4096 + ks * 1024 + lo);
        }
        __builtin_amdgcn_s_setprio(1);
#pragma unroll
        for (int ks = 0; ks < 4; ks++)
#pragma unroll
            for (int t = 0; t < 2; t++)
#pragma unroll
                for (int pt = 0; pt < 2; pt++) MFMA(wf[t][ks].v, bh1[ks][pt].v, acc[t][pt]);
        __builtin_amdgcn_s_setprio(0);
#pragma unroll
        for (int t = 0; t < 2; t++) {
            const int ft = 2 * fp + t;
            const int ksp = ft & 1, hi = ft >> 1;
#pragma unroll
            for (int pt = 0; pt < 2; pt++) {
                bh2[ksp][pt].w[hi * 2 + 0] = pkmax0(pkrtz(acc[t][pt][0], acc[t][pt][1]));
                bh2[ksp][pt].w[hi * 2 + 1] = pkmax0(pkrtz(acc[t][pt][2], acc[t][pt][3]));
            }
        }
    }

    // ---- W3 (64->64): 2 tile-pairs ----
    ABu bh3[2][2];
#pragma unroll
    for (int fp = 0; fp < 2; fp++) {
        const int f0 = 2 * fp, f1 = 2 * fp + 1;
        f32x4 b0v = *(const f32x4*)&b3[f0 * 16 + 4 * g];
        f32x4 b1v = *(const f32x4*)&b3[f1 * 16 + 4 * g];
        f32x4 acc[2][2] = {{b0v, b0v}, {b1v, b1v}};
        ABu wf[2][2];
#pragma unroll
        for (int ks = 0; ks < 2; ks++) {
            wf[0][ks].u = *(const uint4*)(WB + W3OFF + f0 * 2048 + ks * 1024 + lo);
            wf[1][ks].u = *(const uint4*)(WB + W3OFF + f1 * 2048 + ks * 1024 + lo);
        }
        __builtin_amdgcn_s_setprio(1);
#pragma unroll
        for (int ks = 0; ks < 2; ks++)
#pragma unroll
            for (int t = 0; t < 2; t++)
#pragma unroll
                for (int pt = 0; pt < 2; pt++) MFMA(wf[t][ks].v, bh2[ks][pt].v, acc[t][pt]);
        __builtin_amdgcn_s_setprio(0);
#pragma unroll
        for (int t = 0; t < 2; t++) {
            const int ft = 2 * fp + t;
            const int ksp = ft & 1, hi = ft >> 1;
#pragma unroll
            for (int pt = 0; pt < 2; pt++) {
                bh3[ksp][pt].w[hi * 2 + 0] = pkmax0(pkrtz(acc[t][pt][0], acc[t][pt][1]));
                bh3[ksp][pt].w[hi * 2 + 1] = pkmax0(pkrtz(acc[t][pt][2], acc[t][pt][3]));
            }
        }
    }

    // ---- W4 (64->64): 2 tile-pairs, W5 dot folded (f32 epilogue) ----
    float s0 = 0.f, s1 = 0.f;
#pragma unroll
    for (int fp = 0; fp < 2; fp++) {
        const int f0 = 2 * fp, f1 = 2 * fp + 1;
        f32x4 b0v = *(const f32x4*)&b4[f0 * 16 + 4 * g];
        f32x4 b1v = *(const f32x4*)&b4[f1 * 16 + 4 * g];
        f32x4 w0v = *(const f32x4*)&W5[f0 * 16 + 4 * g];
        f32x4 w1v = *(const f32x4*)&W5[f1 * 16 + 4 * g];
        f32x4 acc[2][2] = {{b0v, b0v}, {b1v, b1v}};
        ABu wf[2][2];
#pragma unroll
        for (int ks = 0; ks < 2; ks++) {
            wf[0][ks].u = *(const uint4*)(WB + W4OFF + f0 * 2048 + ks * 1024 + lo);
            wf[1][ks].u = *(const uint4*)(WB + W4OFF + f1 * 2048 + ks * 1024 + lo);
        }
        __builtin_amdgcn_s_setprio(1);
#pragma unroll
        for (int ks = 0; ks < 2; ks++)
#pragma unroll
            for (int t = 0; t < 2; t++)
#pragma unroll
                for (int pt = 0; pt < 2; pt++) MFMA(wf[t][ks].v, bh3[ks][pt].v, acc[t][pt]);
        __builtin_amdgcn_s_setprio(0);
#pragma unroll
        for (int r = 0; r < 4; r++) {
            s0 += fmaxf(acc[0][0][r], 0.f) * w0v[r] + fmaxf(acc[1][0][r], 0.f) * w1v[r];
            s1 += fmaxf(acc[0][1][r], 0.f) * w0v[r] + fmaxf(acc[1][1][r], 0.f) * w1v[r];
        }
    }

    // ---- reduce over g-lanes, write outputs ----
    float b5s = b5[0];
    s0 += __shfl_xor(s0, 16); s0 += __shfl_xor(s0, 32);
    s1 += __shfl_xor(s1, 16); s1 += __shfl_xor(s1, 32);
    if (lane < 16) {
        out[(pw + 0) * NB + qb + c] = s0 + b5s;
        out[(pw + 1) * NB + qb + c] = s1 + b5s;
    }
}

extern "C" void kernel_launch(void* const* d_in, const int* in_sizes, int n_in,
                              void* d_out, int out_size, void* d_ws, size_t ws_size,
                              hipStream_t stream) {
    const float* x  = (const float*)d_in[0];
    const float* y  = (const float*)d_in[1];
    const float* W0 = (const float*)d_in[2];
    const float* b0 = (const float*)d_in[3];
    const float* W1 = (const float*)d_in[4];
    const float* b1 = (const float*)d_in[5];
    const float* W2 = (const float*)d_in[6];
    const float* b2 = (const float*)d_in[7];
    const float* W3 = (const float*)d_in[8];
    const float* b3 = (const float*)d_in[9];
    const float* W4 = (const float*)d_in[10];
    const float* b4 = (const float*)d_in[11];
    const float* W5 = (const float*)d_in[12];
    const float* b5 = (const float*)d_in[13];
    float* out = (float*)d_out;

    char* ws = (char*)d_ws;
    _Float16* Af   = (_Float16*)ws;                 // 1024*128 f16 = 256KB
    _Float16* Cf   = (_Float16*)(ws + 262144);      // 256KB
    _Float16* Wimg = (_Float16*)(ws + 524288);      // 64KB fragment-major image

    prep_ac<<<2048, 128, 0, stream>>>(x, y, W0, b0, Af, Cf);
    prep_img<<<128, 256, 0, stream>>>(W1, W2, W3, W4, Wimg);
    critic_main<<<4096, 512, 0, stream>>>(Af, Cf, Wimg,
                                          b1, b2, b3, b4, W5, b5, out);
}